// Round 1
// baseline (263.649 us; speedup 1.0000x reference)
//
#include <hip/hip_runtime.h>
#include <math.h>

#define DIM 4096
#define CAP 8192
#define EPS 1e-8f

// ---------------------------------------------------------------------------
// Kernel A: weighted[row] = (dot(mb[row],q) / max(||q||*||mb[row]||, eps))
//                           * importance[row] * exp(-0.001*age[row])
// One block per row, 256 threads, float4 loads. Query is re-read per block but
// is 16 KiB and L2/L3 resident.
// ---------------------------------------------------------------------------
__global__ __launch_bounds__(256) void score_kernel(
    const float* __restrict__ q,
    const float* __restrict__ mb,
    const float* __restrict__ imp,
    const float* __restrict__ age,
    float* __restrict__ weighted)
{
    const int row = blockIdx.x;
    const float4* __restrict__ mrow = (const float4*)(mb + (size_t)row * DIM);
    const float4* __restrict__ q4   = (const float4*)q;

    float dot = 0.f, msq = 0.f, qsq = 0.f;
    for (int i = threadIdx.x; i < DIM / 4; i += 256) {
        float4 m  = mrow[i];
        float4 qq = q4[i];
        dot += m.x * qq.x + m.y * qq.y + m.z * qq.z + m.w * qq.w;
        msq += m.x * m.x + m.y * m.y + m.z * m.z + m.w * m.w;
        qsq += qq.x * qq.x + qq.y * qq.y + qq.z * qq.z + qq.w * qq.w;
    }

    // wave (64-lane) shuffle reduction of the 3 partials
    for (int off = 32; off > 0; off >>= 1) {
        dot += __shfl_down(dot, off, 64);
        msq += __shfl_down(msq, off, 64);
        qsq += __shfl_down(qsq, off, 64);
    }

    __shared__ float sdot[4], smsq[4], sqsq[4];
    const int wave = threadIdx.x >> 6;
    const int lane = threadIdx.x & 63;
    if (lane == 0) { sdot[wave] = dot; smsq[wave] = msq; sqsq[wave] = qsq; }
    __syncthreads();

    if (threadIdx.x == 0) {
        float d = 0.f, ms = 0.f, qs = 0.f;
        for (int w = 0; w < 4; ++w) { d += sdot[w]; ms += smsq[w]; qs += sqsq[w]; }
        float denom = fmaxf(sqrtf(qs) * sqrtf(ms), EPS);
        weighted[row] = (d / denom) * imp[row] * expf(-0.001f * age[row]);
    }
}

// ---------------------------------------------------------------------------
// Kernel B: top-k (repeated argmax in LDS, lowest-index tie-break to match
// jax.lax.top_k) + gather-mean of the k rows into retrieved[DIM].
// Single block of 1024 threads (16 waves).
// ---------------------------------------------------------------------------
__global__ __launch_bounds__(1024) void topk_gather_kernel(
    const float* __restrict__ weighted,
    const float* __restrict__ mb,
    const int* __restrict__ topk_ptr,
    float* __restrict__ retrieved)
{
    __shared__ float wv[CAP];          // 32 KiB
    __shared__ float rv[16];
    __shared__ int   ri[16];
    __shared__ int   sidx[64];

    const int tid = threadIdx.x;
    for (int i = tid; i < CAP; i += 1024) wv[i] = weighted[i];
    __syncthreads();

    int k = *topk_ptr;
    if (k < 1) k = 1;
    if (k > 64) k = 64;

    for (int it = 0; it < k; ++it) {
        // local scan: ascending index, strict > keeps the lowest index
        float bv = -INFINITY; int bi = 0x7fffffff;
        for (int i = tid; i < CAP; i += 1024) {
            float v = wv[i];
            if (v > bv) { bv = v; bi = i; }
        }
        // wave shuffle argmax with index tie-break
        for (int off = 32; off > 0; off >>= 1) {
            float ov = __shfl_down(bv, off, 64);
            int   oi = __shfl_down(bi, off, 64);
            if (ov > bv || (ov == bv && oi < bi)) { bv = ov; bi = oi; }
        }
        const int wave = tid >> 6;
        const int lane = tid & 63;
        if (lane == 0) { rv[wave] = bv; ri[wave] = bi; }
        __syncthreads();
        if (tid == 0) {
            float best = rv[0]; int besti = ri[0];
            for (int w = 1; w < 16; ++w) {
                if (rv[w] > best || (rv[w] == best && ri[w] < besti)) {
                    best = rv[w]; besti = ri[w];
                }
            }
            sidx[it] = besti;
            wv[besti] = -INFINITY;   // remove for next pass
        }
        __syncthreads();
    }

    // gather-mean of the k selected rows
    const float inv_k = 1.0f / (float)k;
    for (int i = tid; i < DIM / 4; i += 1024) {
        float4 acc = make_float4(0.f, 0.f, 0.f, 0.f);
        for (int r = 0; r < k; ++r) {
            const float4* __restrict__ row = (const float4*)(mb + (size_t)sidx[r] * DIM);
            float4 v = row[i];
            acc.x += v.x; acc.y += v.y; acc.z += v.z; acc.w += v.w;
        }
        acc.x *= inv_k; acc.y *= inv_k; acc.z *= inv_k; acc.w *= inv_k;
        ((float4*)retrieved)[i] = acc;
    }
}

// ---------------------------------------------------------------------------
// Kernel C: out[j] = dot(W_dec[j,:], retrieved) + b_dec[j]
// One block per output element, 256 threads, float4 loads.
// ---------------------------------------------------------------------------
__global__ __launch_bounds__(256) void decode_kernel(
    const float* __restrict__ W,
    const float* __restrict__ b,
    const float* __restrict__ r,
    float* __restrict__ out)
{
    const int j = blockIdx.x;
    const float4* __restrict__ wrow = (const float4*)(W + (size_t)j * DIM);
    const float4* __restrict__ r4   = (const float4*)r;

    float acc = 0.f;
    for (int i = threadIdx.x; i < DIM / 4; i += 256) {
        float4 w = wrow[i];
        float4 v = r4[i];
        acc += w.x * v.x + w.y * v.y + w.z * v.z + w.w * v.w;
    }
    for (int off = 32; off > 0; off >>= 1) acc += __shfl_down(acc, off, 64);

    __shared__ float sacc[4];
    const int wave = threadIdx.x >> 6;
    const int lane = threadIdx.x & 63;
    if (lane == 0) sacc[wave] = acc;
    __syncthreads();
    if (threadIdx.x == 0) {
        float s = sacc[0] + sacc[1] + sacc[2] + sacc[3];
        out[j] = s + b[j];
    }
}

extern "C" void kernel_launch(void* const* d_in, const int* in_sizes, int n_in,
                              void* d_out, int out_size, void* d_ws, size_t ws_size,
                              hipStream_t stream) {
    const float* query      = (const float*)d_in[0];
    const float* memory     = (const float*)d_in[1];
    const float* importance = (const float*)d_in[2];
    const float* age        = (const float*)d_in[3];
    const float* W_dec      = (const float*)d_in[4];
    const float* b_dec      = (const float*)d_in[5];
    const int*   top_k      = (const int*)d_in[6];

    float* weighted  = (float*)d_ws;                 // CAP floats
    float* retrieved = (float*)d_ws + CAP;           // DIM floats
    float* out       = (float*)d_out;

    score_kernel<<<CAP, 256, 0, stream>>>(query, memory, importance, age, weighted);
    topk_gather_kernel<<<1, 1024, 0, stream>>>(weighted, memory, top_k, retrieved);
    decode_kernel<<<DIM, 256, 0, stream>>>(W_dec, b_dec, retrieved, out);
}